// Round 3
// baseline (154.556 us; speedup 1.0000x reference)
//
#include <hip/hip_runtime.h>
#include <math.h>

constexpr int B_ = 8192;
constexpr int N_ = 1024;
constexpr int NTHREADS = 256;
constexpr int BPB = 4;                      // batches per block in point phase
constexpr int NBLOCKS = B_ / BPB;           // 2048 blocks -> 8 blocks/CU
constexpr float SCALE = 1.0f / ((float)B_ * (float)N_);

// R = Rx(a) @ Ry(b) @ Rz(c), row-major 3x3 (matches reference euler_to_matrix_xyz)
__device__ __forceinline__ void euler_to_mat(float a, float b, float c, float R[9]) {
    float ca = cosf(a), sa = sinf(a);
    float cb = cosf(b), sb = sinf(b);
    float cc = cosf(c), sc = sinf(c);
    R[0] = cb * cc;                R[1] = -cb * sc;               R[2] = sb;
    R[3] = ca * sc + sa * sb * cc; R[4] = ca * cc - sa * sb * sc; R[5] = -sa * cb;
    R[6] = sa * sc - ca * sb * cc; R[7] = sa * cc + ca * sb * sc; R[8] = ca * cb;
}

__device__ __forceinline__ void compute_M(const float* __restrict__ pred,
                                          const float* __restrict__ mode,
                                          const float* __restrict__ gt,
                                          int b, float M[9]) {
    float m1 = pred[b * 4 + 0], m2 = pred[b * 4 + 1];
    float m3 = pred[b * 4 + 2], m4 = pred[b * 4 + 3];
    float sgn = (mode[b] > 0.5f) ? 1.0f : -1.0f;
    float e2 = sgn * asinf(sqrtf(m3 * m3 / (m1 * m1 + m2 * m2 + m3 * m3)));
    float e3 = atan2f(m4, m3 / (sinf(e2) + 1e-9f));
    float tmp = cosf(e2) * cosf(e3);
    float e1 = atan2f(m2 / tmp, m1 / tmp);
    e3 = (e3 > 0.0f) ? e3 : (e3 + 6.2831854820251465f); // float32(2*pi)
    float P[9], G[9];
    euler_to_mat(e1, e2, e3, P);
    euler_to_mat(gt[b * 3 + 0], gt[b * 3 + 1], gt[b * 3 + 2], G);
    #pragma unroll
    for (int i = 0; i < 9; ++i) M[i] = P[i] - G[i];
}

// ---------- Phase 1: all-lanes-parallel M computation (8192 threads) ----------
__global__ __launch_bounds__(256)
void prep_M_kernel(const float* __restrict__ pred, const float* __restrict__ mode,
                   const float* __restrict__ gt, float* __restrict__ Mout) {
    int b = blockIdx.x * blockDim.x + threadIdx.x;
    if (b >= B_) return;
    float M[9];
    compute_M(pred, mode, gt, b, M);
    #pragma unroll
    for (int i = 0; i < 9; ++i) Mout[b * 9 + i] = M[i];
}

__device__ __forceinline__ float dist3(float px, float py, float pz, const float* M) {
    float dx = px * M[0] + py * M[3] + pz * M[6];
    float dy = px * M[1] + py * M[4] + pz * M[7];
    float dz = px * M[2] + py * M[5] + pz * M[8];
    return sqrtf(dx * dx + dy * dy + dz * dz);
}

// ---------- Phase 2: streaming point kernel, 4 batches/block, no barriers ----------
__global__ __launch_bounds__(NTHREADS)
void point_kernel(const float* __restrict__ point,   // (B,N,3)
                  const float* __restrict__ Mg,      // (B,9)
                  float* __restrict__ partial)       // (NBLOCKS,)
{
    const int b0 = blockIdx.x * BPB;
    const int t  = threadIdx.x;

    // M for 4 batches: wave-uniform addresses on const __restrict__ -> s_load path.
    float M[BPB][9];
    const float* mg = Mg + (size_t)b0 * 9;
    #pragma unroll
    for (int ib = 0; ib < BPB; ++ib)
        #pragma unroll
        for (int i = 0; i < 9; ++i) M[ib][i] = mg[ib * 9 + i];

    // Issue all 12 float4 loads up front (independent -> 12 in flight per thread).
    const float4* gp4 = (const float4*)(point + (size_t)b0 * (N_ * 3));
    float4 P[BPB][3];
    #pragma unroll
    for (int ib = 0; ib < BPB; ++ib)
        #pragma unroll
        for (int k = 0; k < 3; ++k)
            P[ib][k] = gp4[ib * (N_ * 3 / 4) + 3 * t + k];

    float local = 0.0f;
    #pragma unroll
    for (int ib = 0; ib < BPB; ++ib) {
        const float4 p0 = P[ib][0], p1 = P[ib][1], p2 = P[ib][2];
        local += dist3(p0.x, p0.y, p0.z, M[ib])
               + dist3(p0.w, p1.x, p1.y, M[ib])
               + dist3(p1.z, p1.w, p2.x, M[ib])
               + dist3(p2.y, p2.z, p2.w, M[ib]);
    }

    // Tail reduce: wave64 shuffle -> LDS -> one store per block.
    __shared__ float swave[NTHREADS / 64];
    #pragma unroll
    for (int off = 32; off > 0; off >>= 1)
        local += __shfl_down(local, off, 64);
    if ((t & 63) == 0) swave[t >> 6] = local;
    __syncthreads();
    if (t == 0) partial[blockIdx.x] = swave[0] + swave[1] + swave[2] + swave[3];
}

// ---------- Phase 3: reduce 2048 partials -> scalar ----------
__global__ __launch_bounds__(1024)
void reduce_kernel(const float* __restrict__ partial, float* __restrict__ out) {
    __shared__ float swave[1024 / 64];
    const int t = threadIdx.x;
    float local = 0.0f;
    #pragma unroll
    for (int i = 0; i < NBLOCKS / 1024; ++i) local += partial[t + 1024 * i];
    #pragma unroll
    for (int off = 32; off > 0; off >>= 1)
        local += __shfl_down(local, off, 64);
    if ((t & 63) == 0) swave[t >> 6] = local;
    __syncthreads();
    if (t == 0) {
        float s = 0.0f;
        #pragma unroll
        for (int i = 0; i < 1024 / 64; ++i) s += swave[i];
        out[0] = s * SCALE;
    }
}

// ---------- Fallback (ws too small): fused, redundant per-thread M ----------
__global__ __launch_bounds__(NTHREADS)
void fused_kernel(const float* __restrict__ pred, const float* __restrict__ mode,
                  const float* __restrict__ gt, const float* __restrict__ point,
                  float* __restrict__ out) {
    const int b = blockIdx.x;
    const int t = threadIdx.x;
    __shared__ float swave[NTHREADS / 64];
    float M[9];
    compute_M(pred, mode, gt, b, M);
    const float4* gp = (const float4*)(point + (size_t)b * (N_ * 3));
    float4 p0 = gp[3 * t + 0];
    float4 p1 = gp[3 * t + 1];
    float4 p2 = gp[3 * t + 2];
    float local = dist3(p0.x, p0.y, p0.z, M)
                + dist3(p0.w, p1.x, p1.y, M)
                + dist3(p1.z, p1.w, p2.x, M)
                + dist3(p2.y, p2.z, p2.w, M);
    #pragma unroll
    for (int off = 32; off > 0; off >>= 1)
        local += __shfl_down(local, off, 64);
    if ((t & 63) == 0) swave[t >> 6] = local;
    __syncthreads();
    if (t == 0)
        atomicAdd(out, (swave[0] + swave[1] + swave[2] + swave[3]) * SCALE);
}

extern "C" void kernel_launch(void* const* d_in, const int* in_sizes, int n_in,
                              void* d_out, int out_size, void* d_ws, size_t ws_size,
                              hipStream_t stream) {
    const float* pred  = (const float*)d_in[0];
    const float* mode  = (const float*)d_in[1];
    const float* gt    = (const float*)d_in[2];
    const float* point = (const float*)d_in[3];
    float* out = (float*)d_out;

    const size_t need = (size_t)(B_ * 9 + NBLOCKS) * sizeof(float);
    if (ws_size >= need) {
        float* Mg      = (float*)d_ws;
        float* partial = Mg + B_ * 9;
        prep_M_kernel<<<B_ / 256, 256, 0, stream>>>(pred, mode, gt, Mg);
        point_kernel<<<NBLOCKS, NTHREADS, 0, stream>>>(point, Mg, partial);
        reduce_kernel<<<1, 1024, 0, stream>>>(partial, out);
    } else {
        hipMemsetAsync(out, 0, sizeof(float), stream);
        fused_kernel<<<B_, NTHREADS, 0, stream>>>(pred, mode, gt, point, out);
    }
}

// Round 5
// 152.662 us; speedup vs baseline: 1.0124x; 1.0124x over previous
//
#include <hip/hip_runtime.h>
#include <math.h>

constexpr int B_ = 8192;
constexpr int N_ = 1024;
constexpr int NTHREADS = 256;
constexpr int WPB = NTHREADS / 64;        // 4 waves/block, one batch per wave
constexpr int NBLOCKS = B_ / WPB;         // 2048 blocks
constexpr float SCALE = 1.0f / ((float)B_ * (float)N_);

// Native vector type for nontemporal builtins (HIP_vector_type is rejected).
typedef float vfloat4 __attribute__((ext_vector_type(4)));

// R = Rx(a) @ Ry(b) @ Rz(c), row-major 3x3 (matches reference euler_to_matrix_xyz)
__device__ __forceinline__ void euler_to_mat(float a, float b, float c, float R[9]) {
    float ca = cosf(a), sa = sinf(a);
    float cb = cosf(b), sb = sinf(b);
    float cc = cosf(c), sc = sinf(c);
    R[0] = cb * cc;                R[1] = -cb * sc;               R[2] = sb;
    R[3] = ca * sc + sa * sb * cc; R[4] = ca * cc - sa * sb * sc; R[5] = -sa * cb;
    R[6] = sa * sc - ca * sb * cc; R[7] = sa * cc + ca * sb * sc; R[8] = ca * cb;
}

__device__ __forceinline__ void compute_M(const float* __restrict__ pred,
                                          const float* __restrict__ mode,
                                          const float* __restrict__ gt,
                                          int b, float M[9]) {
    float m1 = pred[b * 4 + 0], m2 = pred[b * 4 + 1];
    float m3 = pred[b * 4 + 2], m4 = pred[b * 4 + 3];
    float sgn = (mode[b] > 0.5f) ? 1.0f : -1.0f;
    float e2 = sgn * asinf(sqrtf(m3 * m3 / (m1 * m1 + m2 * m2 + m3 * m3)));
    float e3 = atan2f(m4, m3 / (sinf(e2) + 1e-9f));
    float tmp = cosf(e2) * cosf(e3);
    float e1 = atan2f(m2 / tmp, m1 / tmp);
    e3 = (e3 > 0.0f) ? e3 : (e3 + 6.2831854820251465f); // float32(2*pi)
    float P[9], G[9];
    euler_to_mat(e1, e2, e3, P);
    euler_to_mat(gt[b * 3 + 0], gt[b * 3 + 1], gt[b * 3 + 2], G);
    #pragma unroll
    for (int i = 0; i < 9; ++i) M[i] = P[i] - G[i];
}

__device__ __forceinline__ float dist3(float px, float py, float pz, const float* M) {
    float dx = px * M[0] + py * M[3] + pz * M[6];
    float dy = px * M[1] + py * M[4] + pz * M[7];
    float dz = px * M[2] + py * M[5] + pz * M[8];
    return sqrtf(dx * dx + dy * dy + dz * dz);
}

// ---------- Main: one batch per wave, no LDS, no barriers, one dispatch ----------
__global__ __launch_bounds__(NTHREADS)
void fused_main(const float* __restrict__ pred, const float* __restrict__ mode,
                const float* __restrict__ gt, const float* __restrict__ point,
                float* __restrict__ partial)          // (B_,) one entry per wave/batch
{
    const int wave = threadIdx.x >> 6;
    const int lane = threadIdx.x & 63;
    const int b    = blockIdx.x * WPB + wave;

    // 1) Issue ALL 12 streaming loads first (independent of M -> overlap its latency
    //    with the transcendental chain below). Lane reads 3 consecutive float4s
    //    (= 4 whole points) per chunk; wave covers a contiguous 3 KB region per
    //    chunk -> every fetched line fully used. Nontemporal: read-once stream.
    const vfloat4* gp4 = (const vfloat4*)(point + (size_t)b * (N_ * 3));
    vfloat4 P[4][3];
    #pragma unroll
    for (int j = 0; j < 4; ++j)
        #pragma unroll
        for (int k = 0; k < 3; ++k)
            P[j][k] = __builtin_nontemporal_load(&gp4[192 * j + 3 * lane + k]);

    // 2) M computed redundantly on all 64 lanes (wave-uniform -> zero divergence,
    //    no LDS broadcast needed). ~250 VALU insts, hidden under HBM latency.
    float M[9];
    compute_M(pred, mode, gt, b, M);

    // 3) 16 points per lane.
    float local = 0.0f;
    #pragma unroll
    for (int j = 0; j < 4; ++j) {
        const vfloat4 p0 = P[j][0], p1 = P[j][1], p2 = P[j][2];
        local += dist3(p0.x, p0.y, p0.z, M)
               + dist3(p0.w, p1.x, p1.y, M)
               + dist3(p1.z, p1.w, p2.x, M)
               + dist3(p2.y, p2.z, p2.w, M);
    }

    // 4) Wave-local shuffle reduce; lane 0 stores this batch's sum.
    #pragma unroll
    for (int off = 32; off > 0; off >>= 1)
        local += __shfl_down(local, off, 64);
    if (lane == 0) partial[b] = local;
}

// ---------- Final: reduce 8192 partials -> scalar ----------
__global__ __launch_bounds__(1024)
void reduce_kernel(const float* __restrict__ partial, float* __restrict__ out) {
    __shared__ float swave[1024 / 64];
    const int t = threadIdx.x;
    float local = 0.0f;
    #pragma unroll
    for (int i = 0; i < B_ / 1024; ++i) local += partial[t + 1024 * i];
    #pragma unroll
    for (int off = 32; off > 0; off >>= 1)
        local += __shfl_down(local, off, 64);
    if ((t & 63) == 0) swave[t >> 6] = local;
    __syncthreads();
    if (t == 0) {
        float s = 0.0f;
        #pragma unroll
        for (int i = 0; i < 1024 / 64; ++i) s += swave[i];
        out[0] = s * SCALE;
    }
}

// ---------- Fallback (ws too small): same main but atomic into out ----------
__global__ __launch_bounds__(NTHREADS)
void fused_atomic(const float* __restrict__ pred, const float* __restrict__ mode,
                  const float* __restrict__ gt, const float* __restrict__ point,
                  float* __restrict__ out) {
    const int wave = threadIdx.x >> 6;
    const int lane = threadIdx.x & 63;
    const int b    = blockIdx.x * WPB + wave;
    const vfloat4* gp4 = (const vfloat4*)(point + (size_t)b * (N_ * 3));
    vfloat4 P[4][3];
    #pragma unroll
    for (int j = 0; j < 4; ++j)
        #pragma unroll
        for (int k = 0; k < 3; ++k)
            P[j][k] = __builtin_nontemporal_load(&gp4[192 * j + 3 * lane + k]);
    float M[9];
    compute_M(pred, mode, gt, b, M);
    float local = 0.0f;
    #pragma unroll
    for (int j = 0; j < 4; ++j) {
        const vfloat4 p0 = P[j][0], p1 = P[j][1], p2 = P[j][2];
        local += dist3(p0.x, p0.y, p0.z, M)
               + dist3(p0.w, p1.x, p1.y, M)
               + dist3(p1.z, p1.w, p2.x, M)
               + dist3(p2.y, p2.z, p2.w, M);
    }
    #pragma unroll
    for (int off = 32; off > 0; off >>= 1)
        local += __shfl_down(local, off, 64);
    if (lane == 0) atomicAdd(out, local * SCALE);
}

extern "C" void kernel_launch(void* const* d_in, const int* in_sizes, int n_in,
                              void* d_out, int out_size, void* d_ws, size_t ws_size,
                              hipStream_t stream) {
    const float* pred  = (const float*)d_in[0];
    const float* mode  = (const float*)d_in[1];
    const float* gt    = (const float*)d_in[2];
    const float* point = (const float*)d_in[3];
    float* out = (float*)d_out;

    if (ws_size >= (size_t)B_ * sizeof(float)) {
        float* partial = (float*)d_ws;
        fused_main<<<NBLOCKS, NTHREADS, 0, stream>>>(pred, mode, gt, point, partial);
        reduce_kernel<<<1, 1024, 0, stream>>>(partial, out);
    } else {
        (void)hipMemsetAsync(out, 0, sizeof(float), stream);
        fused_atomic<<<NBLOCKS, NTHREADS, 0, stream>>>(pred, mode, gt, point, out);
    }
}